// Round 5
// baseline (591.025 us; speedup 1.0000x reference)
//
#include <hip/hip_runtime.h>
#include <hip/hip_bf16.h>

typedef unsigned short u16;
typedef __attribute__((ext_vector_type(8))) short short8;
typedef __attribute__((ext_vector_type(4))) short short4_t;
typedef __attribute__((ext_vector_type(4))) float f32x4;

#define MFMA16(a, b, c) __builtin_amdgcn_mfma_f32_16x16x32_bf16((a), (b), (c), 0, 0, 0)
#define GLOAD_LDS16(gp, lp)                                          \
  __builtin_amdgcn_global_load_lds(                                  \
      (const __attribute__((address_space(1))) void*)(gp),           \
      (__attribute__((address_space(3))) void*)(lp), 16, 0, 0)

__device__ __forceinline__ float us2f(u16 u) {
  union { unsigned int i; float f; } c; c.i = ((unsigned int)u) << 16; return c.f;
}
__device__ __forceinline__ u16 f2us(float f) {
  union { float f; unsigned int i; } c; c.f = f;
  return (u16)((c.i + 0x7fffu + ((c.i >> 16) & 1u)) >> 16);
}
// packed 2xf32 -> 2xbf16 (v_cvt_pk_bf16_f32 on gfx950); a in low 16, b in high
__device__ __forceinline__ unsigned int f2us2(float a, float b) {
  union { __hip_bfloat162 h; unsigned int u; } c;
  c.h = __float22bfloat162_rn(float2{a, b});
  return c.u;
}

// ---------------------------------------------------------------------------
// Fused f32 -> bf16 convert for the 7 big tensors (X q/k/v + 4 weights).
// ---------------------------------------------------------------------------
__global__ __launch_bounds__(256) void cvt_all_kernel(
    const float* x0, const float* x1, const float* x2, const float* w0,
    const float* w1, const float* w2, const float* w3, u16* y0, u16* y1,
    u16* y2, u16* z0, u16* z1, u16* z2, u16* z3) {
  const int z = blockIdx.z;
  const float* src; u16* dst; int n;
  switch (z) {
    case 0: src = x0; dst = y0; n = 4194304; break;
    case 1: src = x1; dst = y1; n = 4194304; break;
    case 2: src = x2; dst = y2; n = 4194304; break;
    case 3: src = w0; dst = z0; n = 1048576; break;
    case 4: src = w1; dst = z1; n = 1048576; break;
    case 5: src = w2; dst = z2; n = 1048576; break;
    default: src = w3; dst = z3; n = 1048576; break;
  }
  const int i = (blockIdx.x * 256 + threadIdx.x) * 8;
  if (i < n) {
    const float4 a = *(const float4*)(src + i);
    const float4 b = *(const float4*)(src + i + 4);
    unsigned int o[4];
    o[0] = f2us2(a.x, a.y); o[1] = f2us2(a.z, a.w);
    o[2] = f2us2(b.x, b.y); o[3] = f2us2(b.z, b.w);
    *(uint4*)(dst + i) = *(uint4*)o;
  }
}

// ---------------------------------------------------------------------------
// GEMM: Y = X @ W^T + bias (validated round 3/4).
// SCATTER && vt:  Y layout [bh][d][s]  (V transposed for attention B-operand)
// SCATTER && !vt: Y layout [bh][s][d]
// ---------------------------------------------------------------------------
template <bool SCATTER, typename OUT>
__device__ __forceinline__ void gemm_body(const u16* __restrict__ X,
                                          const u16* __restrict__ W,
                                          const float* __restrict__ bias,
                                          OUT* __restrict__ Y, int row0, int col0,
                                          bool vt) {
  __shared__ __align__(16) u16 As[128 * 64];
  __shared__ __align__(16) u16 Bs[128 * 64];
  const int tid = threadIdx.x;
  const int lane = tid & 63;
  const int wid = tid >> 6;
  const int wm = wid >> 1, wn = wid & 1;
  const int l15 = lane & 15, l16 = lane >> 4;
  const int lrow = lane >> 3;
  const int lchunk = (lane & 7) ^ lrow;

  f32x4 acc[4][4];
#pragma unroll
  for (int i = 0; i < 4; i++)
#pragma unroll
    for (int j = 0; j < 4; j++) acc[i][j] = (f32x4){0.f, 0.f, 0.f, 0.f};

  for (int k0 = 0; k0 < 1024; k0 += 64) {
#pragma unroll
    for (int i = 0; i < 4; i++) {
      const int rb = wid * 32 + i * 8;
      GLOAD_LDS16(X + (size_t)(row0 + rb + lrow) * 1024 + k0 + lchunk * 8, &As[rb * 64]);
      GLOAD_LDS16(W + (size_t)(col0 + rb + lrow) * 1024 + k0 + lchunk * 8, &Bs[rb * 64]);
    }
    __syncthreads();
#pragma unroll
    for (int kk = 0; kk < 2; kk++) {
      const int ch = kk * 4 + l16;
      short8 af[4], bfr[4];
#pragma unroll
      for (int t = 0; t < 4; t++) {
        const int m = wm * 64 + t * 16 + l15;
        af[t] = *(const short8*)&As[m * 64 + ((ch ^ (m & 7)) * 8)];
        const int n = wn * 64 + t * 16 + l15;
        bfr[t] = *(const short8*)&Bs[n * 64 + ((ch ^ (n & 7)) * 8)];
      }
#pragma unroll
      for (int tm = 0; tm < 4; tm++)
#pragma unroll
        for (int tn = 0; tn < 4; tn++)
          acc[tm][tn] = MFMA16(af[tm], bfr[tn], acc[tm][tn]);
    }
    __syncthreads();
  }

#pragma unroll
  for (int tn = 0; tn < 4; tn++) {
    const int col = col0 + wn * 64 + tn * 16 + l15;
    const float bv = bias[col];
#pragma unroll
    for (int tm = 0; tm < 4; tm++) {
      const int rowb = row0 + wm * 64 + tm * 16 + l16 * 4;  // rows rowb..rowb+3
      if (SCATTER) {
        const int bb = rowb >> 11, ss = rowb & 2047;
        const int hh = col >> 6, dd = col & 63;
        if (vt) {
          // [bh][d][s]: 4 consecutive s -> one 8B store
          unsigned int o[2];
          o[0] = f2us2(acc[tm][tn][0] + bv, acc[tm][tn][1] + bv);
          o[1] = f2us2(acc[tm][tn][2] + bv, acc[tm][tn][3] + bv);
          *(short4_t*)&((u16*)Y)[(((size_t)(bb * 16 + hh)) * 64 + dd) * 2048 + ss] =
              *(short4_t*)o;
        } else {
#pragma unroll
          for (int r = 0; r < 4; r++)
            ((u16*)Y)[(((size_t)(bb * 16 + hh)) * 2048 + ss + r) * 64 + dd] =
                f2us(acc[tm][tn][r] + bv);
        }
      } else {
#pragma unroll
        for (int r = 0; r < 4; r++)
          Y[(size_t)(rowb + r) * 1024 + col] = (OUT)(acc[tm][tn][r] + bv);
      }
    }
  }
}

__global__ __launch_bounds__(256) void qkv_kernel(
    const u16* Xq, const u16* Xk, const u16* Xv, const u16* Wq, const u16* Wk,
    const u16* Wv, const float* bq, const float* bk, const float* bv, u16* Yq,
    u16* Yk, u16* Yv) {
  const int z = blockIdx.z;
  const u16* X = z == 0 ? Xq : (z == 1 ? Xk : Xv);
  const u16* W = z == 0 ? Wq : (z == 1 ? Wk : Wv);
  const float* bi = z == 0 ? bq : (z == 1 ? bk : bv);
  u16* Y = z == 0 ? Yq : (z == 1 ? Yk : Yv);
  gemm_body<true, u16>(X, W, bi, Y, blockIdx.x * 128, blockIdx.y * 128, z == 2);
}

__global__ __launch_bounds__(256) void oproj_kernel(const u16* Xc, const u16* Wo,
                                                    const float* bo, float* out) {
  gemm_body<false, float>(Xc, Wo, bo, out, blockIdx.x * 128, blockIdx.y * 128, false);
}

// ---------------------------------------------------------------------------
// Flash attention, rel-pos terms, NO online softmax (logits bounded — r4
// validated), and now NO K/V LDS staging: K-frags and V^T-frags are loaded
// directly from global as 16B/lane dwordx4 (V pre-transposed by qkv into
// [bh][d][s]). All 4 waves' frag loads hit L1 (16KB tile working set).
// -> zero __syncthreads in the k-loop; only wave-private P-strip LDS + lgkm.
// ---------------------------------------------------------------------------
__global__ __launch_bounds__(256, 4) void attn_kernel(
    const u16* __restrict__ Qg, const u16* __restrict__ Kg,
    const u16* __restrict__ Vtg, const float* __restrict__ relk,
    const float* __restrict__ relv, u16* __restrict__ ctx) {
  __shared__ __align__(16) u16 Qs[64 * 64];
  __shared__ __align__(16) u16 Ps[4][16 * 64];   // per-wave P strip (swizzled)
  __shared__ __align__(4) u16 qrelI[64 * 31];    // Q·relk[j], j=1..31, bf16
  __shared__ __align__(4) u16 wsum[64 * 31];     // in-band p, bf16, write-once

  const int tid = threadIdx.x, lane = tid & 63, wid = tid >> 6;
  const int l15 = lane & 15, l16 = lane >> 4;
  const int bh = blockIdx.y;
  const int b = bh >> 4, h = bh & 15;
  const int q0 = blockIdx.x * 64;
  const u16* Qb = Qg + (size_t)bh * 2048 * 64;
  const u16* Kb = Kg + (size_t)bh * 2048 * 64;
  const u16* Vtb = Vtg + (size_t)bh * 64 * 2048;  // [d][s]

  const int lrow = lane >> 3;
  const int lchunk = (lane & 7) ^ lrow;
  const int qw = wid * 16;
  const int qloc16 = l16 * 4;

  // ---- stage Q tile (once) ----
#pragma unroll
  for (int i = 0; i < 2; i++) {
    const int rb = wid * 16 + i * 8;
    GLOAD_LDS16(Qb + (size_t)(q0 + rb + lrow) * 64 + lchunk * 8, &Qs[rb * 64]);
  }
  // ---- zero wsum ----
  for (int idx = tid; idx < 64 * 31 / 2; idx += 256) ((unsigned int*)wsum)[idx] = 0u;
  // ---- qrelI[q][j-1] = Q[q]·relk[j], j=1..31 ----
  for (int idx = tid; idx < 64 * 31; idx += 256) {
    const int q = idx / 31, j = idx % 31 + 1;
    const u16* qp = Qb + (size_t)(q0 + q) * 64;
    const float* rp = relk + j * 64;
    float s = 0.f;
#pragma unroll
    for (int c = 0; c < 8; c++) {
      const short8 q8 = *(const short8*)(qp + c * 8);
#pragma unroll
      for (int e = 0; e < 8; e++) s += us2f((u16)q8[e]) * rp[c * 8 + e];
    }
    qrelI[q * 31 + (j - 1)] = f2us(s);
  }
  __syncthreads();  // Qs staged + wsum zeroed + qrelI visible

  // ---- hoist Q fragment ----
  short8 aq[2];
  {
    const int m = qw + l15;
    aq[0] = *(const short8*)&Qs[m * 64 + ((l16 ^ (m & 7)) * 8)];
    aq[1] = *(const short8*)&Qs[m * 64 + (((4 + l16) ^ (m & 7)) * 8)];
  }
  // ---- per-row clipped-edge biases: q·relk[0], q·relk[32] ----
  float q0r[4], q32r[4];
#pragma unroll
  for (int r = 0; r < 4; r++) {
    const int ql = qw + qloc16 + r;
    float a0 = 0.f, a32 = 0.f;
#pragma unroll
    for (int c = 0; c < 8; c++) {
      const short8 q8 = *(const short8*)&Qs[ql * 64 + ((c ^ (ql & 7)) * 8)];
#pragma unroll
      for (int e = 0; e < 8; e++) {
        const float qv = us2f((u16)q8[e]);
        a0 += qv * relk[c * 8 + e];
        a32 += qv * relk[32 * 64 + c * 8 + e];
      }
    }
    q0r[r] = a0; q32r[r] = a32;
  }

  float l_acc[4] = {0.f, 0.f, 0.f, 0.f};
  float wl_acc[4] = {0.f, 0.f, 0.f, 0.f};
  float wr_acc[4] = {0.f, 0.f, 0.f, 0.f};
  f32x4 Oacc[4];
#pragma unroll
  for (int t = 0; t < 4; t++) Oacc[t] = (f32x4){0.f, 0.f, 0.f, 0.f};

  u16* Pw = &Ps[wid][0];

  for (int kt = 0; kt < 32; kt++) {
    const int k0 = kt * 64;
    const u16* Kt = Kb + (size_t)k0 * 64;  // K[s=k0..][d]
    const u16* Vt = Vtb + k0;              // V^T[d][s=k0..]

    // ---- direct-from-global fragment loads (16B/lane each) ----
    short8 bk[2][4], bv[2][4];
#pragma unroll
    for (int kk = 0; kk < 2; kk++) {
      const int ch8 = (kk * 4 + l16) * 8;
#pragma unroll
      for (int tn = 0; tn < 4; tn++) {
        const int n = tn * 16 + l15;
        bk[kk][tn] = *(const short8*)(Kt + n * 64 + ch8);
        bv[kk][tn] = *(const short8*)(Vt + (size_t)n * 2048 + ch8);
      }
    }

    // ---- S = Q K^T ----
    f32x4 sac[4];
#pragma unroll
    for (int t = 0; t < 4; t++) sac[t] = (f32x4){0.f, 0.f, 0.f, 0.f};
#pragma unroll
    for (int kk = 0; kk < 2; kk++)
#pragma unroll
      for (int tn = 0; tn < 4; tn++) sac[tn] = MFMA16(aq[kk], bk[kk][tn], sac[tn]);

    // ---- p = exp(s + qrel); bookkeeping; P -> LDS ----
    if (k0 + 79 <= q0 || k0 >= q0 + 79) {
      const bool leftp = (k0 < q0);
#pragma unroll
      for (int tn = 0; tn < 4; tn++) {
        const int k = tn * 16 + l15;
        float p[4];
#pragma unroll
        for (int r = 0; r < 4; r++) {
          p[r] = __expf(sac[tn][r] + (leftp ? q0r[r] : q32r[r]));
          l_acc[r] += p[r];
          if (leftp) wl_acc[r] += p[r]; else wr_acc[r] += p[r];
        }
        const unsigned int w01 = f2us2(p[0], p[1]);
        const unsigned int w23 = f2us2(p[2], p[3]);
        u16* pb = &Pw[qloc16 * 64 + (k & 7)];
        pb[0 * 64 + (((k >> 3) ^ ((qloc16 + 0) & 7)) * 8)] = (u16)w01;
        pb[1 * 64 + (((k >> 3) ^ ((qloc16 + 1) & 7)) * 8)] = (u16)(w01 >> 16);
        pb[2 * 64 + (((k >> 3) ^ ((qloc16 + 2) & 7)) * 8)] = (u16)w23;
        pb[3 * 64 + (((k >> 3) ^ ((qloc16 + 3) & 7)) * 8)] = (u16)(w23 >> 16);
      }
    } else {
#pragma unroll
      for (int tn = 0; tn < 4; tn++) {
        const int kg = k0 + tn * 16 + l15;
#pragma unroll
        for (int r = 0; r < 4; r++) {
          const int ql = qw + qloc16 + r;
          const int dlt = kg - (q0 + ql);
          float bias;
          if (dlt <= -16) bias = q0r[r];
          else if (dlt >= 16) bias = q32r[r];
          else bias = us2f(qrelI[ql * 31 + (dlt + 15)]);
          const float p = __expf(sac[tn][r] + bias);
          l_acc[r] += p;
          if (dlt <= -16) wl_acc[r] += p;
          else if (dlt >= 16) wr_acc[r] += p;
          else wsum[ql * 31 + (dlt + 15)] = f2us(p);  // unique (q,j): no race
          const int k = tn * 16 + l15, q = qloc16 + r;
          Pw[q * 64 + (((k >> 3) ^ (q & 7)) * 8) + (k & 7)] = f2us(p);
        }
      }
    }

    // P strip is wave-private: DS in-order + waitcnt suffices (no barrier).
    asm volatile("s_waitcnt lgkmcnt(0)" ::: "memory");

    // ---- O += P V ----
#pragma unroll
    for (int kk = 0; kk < 2; kk++) {
      const int ch = kk * 4 + l16;
      const short8 ap = *(const short8*)&Pw[l15 * 64 + ((ch ^ (l15 & 7)) * 8)];
#pragma unroll
      for (int tn = 0; tn < 4; tn++) Oacc[tn] = MFMA16(ap, bv[kk][tn], Oacc[tn]);
    }
  }

  // ---- epilogue ----
#pragma unroll
  for (int r = 0; r < 4; r++) {
    l_acc[r] += __shfl_xor(l_acc[r], 1);
    l_acc[r] += __shfl_xor(l_acc[r], 2);
    l_acc[r] += __shfl_xor(l_acc[r], 4);
    l_acc[r] += __shfl_xor(l_acc[r], 8);
    wl_acc[r] += __shfl_xor(wl_acc[r], 1);
    wl_acc[r] += __shfl_xor(wl_acc[r], 2);
    wl_acc[r] += __shfl_xor(wl_acc[r], 4);
    wl_acc[r] += __shfl_xor(wl_acc[r], 8);
    wr_acc[r] += __shfl_xor(wr_acc[r], 1);
    wr_acc[r] += __shfl_xor(wr_acc[r], 2);
    wr_acc[r] += __shfl_xor(wr_acc[r], 4);
    wr_acc[r] += __shfl_xor(wr_acc[r], 8);
  }
  float linv[4];
#pragma unroll
  for (int r = 0; r < 4; r++) {
    linv[r] = 1.f / l_acc[r];
    wl_acc[r] *= linv[r];
    wr_acc[r] *= linv[r];
  }
#pragma unroll
  for (int tn = 0; tn < 4; tn++) {
    const int d = tn * 16 + l15;
    const float rv0 = relv[d];
    const float rv32 = relv[32 * 64 + d];
#pragma unroll
    for (int r = 0; r < 4; r++)
      Oacc[tn][r] = Oacc[tn][r] * linv[r] + wl_acc[r] * rv0 + wr_acc[r] * rv32;
  }
  for (int j = 1; j <= 31; j++) {
    float wv[4];
#pragma unroll
    for (int r = 0; r < 4; r++)
      wv[r] = us2f(wsum[(qw + qloc16 + r) * 31 + (j - 1)]) * linv[r];
#pragma unroll
    for (int tn = 0; tn < 4; tn++) {
      const float rv = relv[j * 64 + tn * 16 + l15];
#pragma unroll
      for (int r = 0; r < 4; r++) Oacc[tn][r] += wv[r] * rv;
    }
  }
#pragma unroll
  for (int tn = 0; tn < 4; tn++) {
    const int d = tn * 16 + l15;
#pragma unroll
    for (int r = 0; r < 4; r++) {
      const int sq = q0 + qw + qloc16 + r;
      ctx[((size_t)b * 2048 + sq) * 1024 + h * 64 + d] = f2us(Oacc[tn][r]);
    }
  }
}

// ---------------------------------------------------------------------------
extern "C" void kernel_launch(void* const* d_in, const int* in_sizes, int n_in,
                              void* d_out, int out_size, void* d_ws, size_t ws_size,
                              hipStream_t stream) {
  u16* qb = (u16*)d_ws;                 // [32][2048][64]
  u16* kb = qb + 4194304;               // [32][2048][64]
  u16* vtb = kb + 4194304;              // [32][64][2048]  (V transposed)
  u16* ctx = vtb + 4194304;             // [2][2048][1024]
  u16* Xq = ctx + 4194304;
  u16* Xk = Xq + 4194304;
  u16* Xv = Xk + 4194304;
  u16* Wqb = Xv + 4194304;
  u16* Wkb = Wqb + 1048576;
  u16* Wvb = Wkb + 1048576;
  u16* Wob = Wvb + 1048576;

  const float* bq = (const float*)d_in[4];
  const float* bk = (const float*)d_in[6];
  const float* bv = (const float*)d_in[8];
  const float* bo = (const float*)d_in[10];
  const float* relk = (const float*)d_in[11];
  const float* relv = (const float*)d_in[12];

  dim3 blk(256);
  cvt_all_kernel<<<dim3(2048, 1, 7), blk, 0, stream>>>(
      (const float*)d_in[0], (const float*)d_in[1], (const float*)d_in[2],
      (const float*)d_in[3], (const float*)d_in[5], (const float*)d_in[7],
      (const float*)d_in[9], Xq, Xk, Xv, Wqb, Wkb, Wvb, Wob);
  qkv_kernel<<<dim3(32, 8, 3), blk, 0, stream>>>(Xq, Xk, Xv, Wqb, Wkb, Wvb, bq,
                                                 bk, bv, qb, kb, vtb);
  attn_kernel<<<dim3(32, 32), blk, 0, stream>>>(qb, kb, vtb, relk, relv, ctx);
  oproj_kernel<<<dim3(32, 8), blk, 0, stream>>>(ctx, Wob, bo, (float*)d_out);
}

// Round 6
// 347.422 us; speedup vs baseline: 1.7012x; 1.7012x over previous
//
#include <hip/hip_runtime.h>
#include <hip/hip_bf16.h>

typedef unsigned short u16;
typedef __attribute__((ext_vector_type(8))) short short8;
typedef __attribute__((ext_vector_type(4))) short short4_t;
typedef __attribute__((ext_vector_type(4))) float f32x4;

#define MFMA16(a, b, c) __builtin_amdgcn_mfma_f32_16x16x32_bf16((a), (b), (c), 0, 0, 0)
#define GLOAD_LDS16(gp, lp)                                          \
  __builtin_amdgcn_global_load_lds(                                  \
      (const __attribute__((address_space(1))) void*)(gp),           \
      (__attribute__((address_space(3))) void*)(lp), 16, 0, 0)
#define SBAR() asm volatile("s_barrier" ::: "memory")
#define WAIT_LGKM0() asm volatile("s_waitcnt lgkmcnt(0)" ::: "memory")

__device__ __forceinline__ float us2f(u16 u) {
  union { unsigned int i; float f; } c; c.i = ((unsigned int)u) << 16; return c.f;
}
__device__ __forceinline__ u16 f2us(float f) {
  union { float f; unsigned int i; } c; c.f = f;
  return (u16)((c.i + 0x7fffu + ((c.i >> 16) & 1u)) >> 16);
}
// packed 2xf32 -> 2xbf16 (v_cvt_pk_bf16_f32); a low 16, b high 16
__device__ __forceinline__ unsigned int f2us2(float a, float b) {
  union { __hip_bfloat162 h; unsigned int u; } c;
  c.h = __float22bfloat162_rn(float2{a, b});
  return c.u;
}

// ---------------------------------------------------------------------------
// Fused f32 -> bf16 convert for the 7 big tensors (X q/k/v + 4 weights).
// ---------------------------------------------------------------------------
__global__ __launch_bounds__(256) void cvt_all_kernel(
    const float* x0, const float* x1, const float* x2, const float* w0,
    const float* w1, const float* w2, const float* w3, u16* y0, u16* y1,
    u16* y2, u16* z0, u16* z1, u16* z2, u16* z3) {
  const int z = blockIdx.z;
  const float* src; u16* dst; int n;
  switch (z) {
    case 0: src = x0; dst = y0; n = 4194304; break;
    case 1: src = x1; dst = y1; n = 4194304; break;
    case 2: src = x2; dst = y2; n = 4194304; break;
    case 3: src = w0; dst = z0; n = 1048576; break;
    case 4: src = w1; dst = z1; n = 1048576; break;
    case 5: src = w2; dst = z2; n = 1048576; break;
    default: src = w3; dst = z3; n = 1048576; break;
  }
  const int i = (blockIdx.x * 256 + threadIdx.x) * 8;
  if (i < n) {
    const float4 a = *(const float4*)(src + i);
    const float4 b = *(const float4*)(src + i + 4);
    unsigned int o[4];
    o[0] = f2us2(a.x, a.y); o[1] = f2us2(a.z, a.w);
    o[2] = f2us2(b.x, b.y); o[3] = f2us2(b.z, b.w);
    *(uint4*)(dst + i) = *(uint4*)o;
  }
}

// ---------------------------------------------------------------------------
// GEMM: Y = X @ W^T + bias (validated r3-r5).
// SCATTER && vt:  Y layout [bh][d][s]  (V transposed for attention B-operand)
// SCATTER && !vt: Y layout [bh][s][d]
// ---------------------------------------------------------------------------
template <bool SCATTER, typename OUT>
__device__ __forceinline__ void gemm_body(const u16* __restrict__ X,
                                          const u16* __restrict__ W,
                                          const float* __restrict__ bias,
                                          OUT* __restrict__ Y, int row0, int col0,
                                          bool vt) {
  __shared__ __align__(16) u16 As[128 * 64];
  __shared__ __align__(16) u16 Bs[128 * 64];
  const int tid = threadIdx.x;
  const int lane = tid & 63;
  const int wid = tid >> 6;
  const int wm = wid >> 1, wn = wid & 1;
  const int l15 = lane & 15, l16 = lane >> 4;
  const int lrow = lane >> 3;
  const int lchunk = (lane & 7) ^ lrow;

  f32x4 acc[4][4];
#pragma unroll
  for (int i = 0; i < 4; i++)
#pragma unroll
    for (int j = 0; j < 4; j++) acc[i][j] = (f32x4){0.f, 0.f, 0.f, 0.f};

  for (int k0 = 0; k0 < 1024; k0 += 64) {
#pragma unroll
    for (int i = 0; i < 4; i++) {
      const int rb = wid * 32 + i * 8;
      GLOAD_LDS16(X + (size_t)(row0 + rb + lrow) * 1024 + k0 + lchunk * 8, &As[rb * 64]);
      GLOAD_LDS16(W + (size_t)(col0 + rb + lrow) * 1024 + k0 + lchunk * 8, &Bs[rb * 64]);
    }
    __syncthreads();
#pragma unroll
    for (int kk = 0; kk < 2; kk++) {
      const int ch = kk * 4 + l16;
      short8 af[4], bfr[4];
#pragma unroll
      for (int t = 0; t < 4; t++) {
        const int m = wm * 64 + t * 16 + l15;
        af[t] = *(const short8*)&As[m * 64 + ((ch ^ (m & 7)) * 8)];
        const int n = wn * 64 + t * 16 + l15;
        bfr[t] = *(const short8*)&Bs[n * 64 + ((ch ^ (n & 7)) * 8)];
      }
#pragma unroll
      for (int tm = 0; tm < 4; tm++)
#pragma unroll
        for (int tn = 0; tn < 4; tn++)
          acc[tm][tn] = MFMA16(af[tm], bfr[tn], acc[tm][tn]);
    }
    __syncthreads();
  }

#pragma unroll
  for (int tn = 0; tn < 4; tn++) {
    const int col = col0 + wn * 64 + tn * 16 + l15;
    const float bv = bias[col];
#pragma unroll
    for (int tm = 0; tm < 4; tm++) {
      const int rowb = row0 + wm * 64 + tm * 16 + l16 * 4;  // rows rowb..rowb+3
      if (SCATTER) {
        const int bb = rowb >> 11, ss = rowb & 2047;
        const int hh = col >> 6, dd = col & 63;
        if (vt) {
          unsigned int o[2];
          o[0] = f2us2(acc[tm][tn][0] + bv, acc[tm][tn][1] + bv);
          o[1] = f2us2(acc[tm][tn][2] + bv, acc[tm][tn][3] + bv);
          *(short4_t*)&((u16*)Y)[(((size_t)(bb * 16 + hh)) * 64 + dd) * 2048 + ss] =
              *(short4_t*)o;
        } else {
#pragma unroll
          for (int r = 0; r < 4; r++)
            ((u16*)Y)[(((size_t)(bb * 16 + hh)) * 2048 + ss + r) * 64 + dd] =
                f2us(acc[tm][tn][r] + bv);
        }
      } else {
#pragma unroll
        for (int r = 0; r < 4; r++)
          Y[(size_t)(rowb + r) * 1024 + col] = (OUT)(acc[tm][tn][r] + bv);
      }
    }
  }
}

__global__ __launch_bounds__(256) void qkv_kernel(
    const u16* Xq, const u16* Xk, const u16* Xv, const u16* Wq, const u16* Wk,
    const u16* Wv, const float* bq, const float* bk, const float* bv, u16* Yq,
    u16* Yk, u16* Yv) {
  const int z = blockIdx.z;
  const u16* X = z == 0 ? Xq : (z == 1 ? Xk : Xv);
  const u16* W = z == 0 ? Wq : (z == 1 ? Wk : Wv);
  const float* bi = z == 0 ? bq : (z == 1 ? bk : bv);
  u16* Y = z == 0 ? Yq : (z == 1 ? Yk : Yv);
  gemm_body<true, u16>(X, W, bi, Y, blockIdx.x * 128, blockIdx.y * 128, z == 2);
}

__global__ __launch_bounds__(256) void oproj_kernel(const u16* Xc, const u16* Wo,
                                                    const float* bo, float* out) {
  gemm_body<false, float>(Xc, Wo, bo, out, blockIdx.x * 128, blockIdx.y * 128, false);
}

// ---------------------------------------------------------------------------
// Flash attention, rel-pos terms, no online softmax (r4-validated bounds).
// r6: K/V staged to LDS via global_load_lds (V from pre-transposed [bh][d][s]
// -> no register transpose), DOUBLE-BUFFERED with raw s_barrier + fine
// s_waitcnt vmcnt(4) (never a full drain mid-loop). Q tile LDS aliases KV
// buffer 1 (prologue-only). qrelJ[64][33] f32 holds all Q·relk biases.
// LDS = 53376 B -> 3 blocks/CU. Grid x = bh so same-bh blocks share an XCD L2.
// ---------------------------------------------------------------------------
__global__ __launch_bounds__(256) void attn_kernel(
    const u16* __restrict__ Qg, const u16* __restrict__ Kg,
    const u16* __restrict__ Vtg, const float* __restrict__ relk,
    const float* __restrict__ relv, u16* __restrict__ ctx) {
  __shared__ __align__(16) u16 KVs[2][8192];     // per buf: K [0,4096), V^T [4096,8192)
  __shared__ __align__(16) u16 Ps[4][1024];      // per-wave P strip (swizzled)
  __shared__ __align__(16) float qrelJ[64 * 33]; // Q[q]·relk[j], j=0..32
  __shared__ __align__(4) u16 wsum[64 * 31];     // in-band p, write-once, wave-private rows

  const int tid = threadIdx.x, lane = tid & 63, wid = tid >> 6;
  const int l15 = lane & 15, l16 = lane >> 4;
  const int bh = blockIdx.x;                     // x = bh: same-bh -> same XCD
  const int b = bh >> 4, h = bh & 15;
  const int q0 = blockIdx.y * 64;
  const u16* Qb = Qg + (size_t)bh * 2048 * 64;
  const u16* Kb = Kg + (size_t)bh * 2048 * 64;
  const u16* Vtb = Vtg + (size_t)bh * 64 * 2048;  // [d][s]

  const int lrow = lane >> 3;
  const int lchunk = (lane & 7) ^ lrow;
  const int qw = wid * 16;
  const int qloc16 = l16 * 4;

  u16* Qs = &KVs[1][0];  // alias: Q lives in buf1 until tile1 staging (kt=0)

  // ---- prologue: stage Q, zero wsum, fill qrelJ ----
#pragma unroll
  for (int i = 0; i < 2; i++) {
    const int rb = wid * 16 + i * 8;
    GLOAD_LDS16(Qb + (size_t)(q0 + rb + lrow) * 64 + lchunk * 8, &Qs[rb * 64]);
  }
  for (int idx = tid; idx < 64 * 31 / 2; idx += 256) ((unsigned int*)wsum)[idx] = 0u;
  for (int idx = tid; idx < 64 * 33; idx += 256) {
    const int q = idx / 33, j = idx % 33;
    const u16* qp = Qb + (size_t)(q0 + q) * 64;
    const float* rp = relk + j * 64;
    float s = 0.f;
#pragma unroll
    for (int c = 0; c < 8; c++) {
      const short8 q8 = *(const short8*)(qp + c * 8);
#pragma unroll
      for (int e = 0; e < 8; e++) s += us2f((u16)q8[e]) * rp[c * 8 + e];
    }
    qrelJ[q * 33 + j] = s;
  }
  __syncthreads();  // full drain: Q staged, wsum zeroed, qrelJ visible

  // ---- issue tile 0 -> buf0 (4 loads/wave outstanding) ----
  {
    const u16* Kt = Kb;
    const u16* Vt = Vtb;
#pragma unroll
    for (int i = 0; i < 2; i++) {
      const int rb = wid * 16 + i * 8;
      GLOAD_LDS16(Kt + (size_t)(rb + lrow) * 64 + lchunk * 8, &KVs[0][rb * 64]);
    }
#pragma unroll
    for (int i = 0; i < 2; i++) {
      const int rb = wid * 16 + i * 8;
      GLOAD_LDS16(Vt + (size_t)(rb + lrow) * 2048 + lchunk * 8, &KVs[0][4096 + rb * 64]);
    }
  }

  // ---- hoist Q fragment + edge biases (reads Qs=buf1, qrelJ) ----
  short8 aq[2];
  {
    const int m = qw + l15;
    aq[0] = *(const short8*)&Qs[m * 64 + ((l16 ^ (m & 7)) * 8)];
    aq[1] = *(const short8*)&Qs[m * 64 + (((4 + l16) ^ (m & 7)) * 8)];
  }
  float q0r[4], q32r[4];
#pragma unroll
  for (int r = 0; r < 4; r++) {
    const int ql = qw + qloc16 + r;
    q0r[r] = qrelJ[ql * 33];
    q32r[r] = qrelJ[ql * 33 + 32];
  }
  WAIT_LGKM0();  // Qs reads landed before buf1 can be overwritten

  float l_acc[4] = {0.f, 0.f, 0.f, 0.f};
  float wl_acc[4] = {0.f, 0.f, 0.f, 0.f};
  float wr_acc[4] = {0.f, 0.f, 0.f, 0.f};
  f32x4 Oacc[4];
#pragma unroll
  for (int t = 0; t < 4; t++) Oacc[t] = (f32x4){0.f, 0.f, 0.f, 0.f};

  u16* Pw = &Ps[wid][0];

  for (int kt = 0; kt < 32; kt++) {
    SBAR();  // all waves done computing prev tile -> next-buf free to overwrite
    u16* KVc = &KVs[kt & 1][0];
    u16* KVn = &KVs[(kt & 1) ^ 1][0];
    if (kt < 31) {
      const int kn = (kt + 1) * 64;
      const u16* Kt = Kb + (size_t)kn * 64;
      const u16* Vt = Vtb + kn;
#pragma unroll
      for (int i = 0; i < 2; i++) {
        const int rb = wid * 16 + i * 8;
        GLOAD_LDS16(Kt + (size_t)(rb + lrow) * 64 + lchunk * 8, &KVn[rb * 64]);
      }
#pragma unroll
      for (int i = 0; i < 2; i++) {
        const int rb = wid * 16 + i * 8;
        GLOAD_LDS16(Vt + (size_t)(rb + lrow) * 2048 + lchunk * 8, &KVn[4096 + rb * 64]);
      }
      asm volatile("s_waitcnt vmcnt(4)" ::: "memory");  // own tile-kt loads done
    } else {
      asm volatile("s_waitcnt vmcnt(0)" ::: "memory");
    }
    SBAR();  // every wave's tile-kt loads are in LDS

    const int k0 = kt * 64;

    // ---- S = Q K^T ----
    f32x4 sac[4];
#pragma unroll
    for (int t = 0; t < 4; t++) sac[t] = (f32x4){0.f, 0.f, 0.f, 0.f};
#pragma unroll
    for (int kk = 0; kk < 2; kk++) {
      const int ch = kk * 4 + l16;
#pragma unroll
      for (int tn = 0; tn < 4; tn++) {
        const int n = tn * 16 + l15;
        const short8 bk = *(const short8*)&KVc[n * 64 + ((ch ^ (n & 7)) * 8)];
        sac[tn] = MFMA16(aq[kk], bk, sac[tn]);
      }
    }

    // ---- p = exp(s + bias); bookkeeping; P -> LDS ----
    if (k0 + 79 <= q0 || k0 >= q0 + 79) {
      const bool leftp = (k0 < q0);
#pragma unroll
      for (int tn = 0; tn < 4; tn++) {
        const int k = tn * 16 + l15;
        float p[4];
#pragma unroll
        for (int r = 0; r < 4; r++) {
          p[r] = __expf(sac[tn][r] + (leftp ? q0r[r] : q32r[r]));
          l_acc[r] += p[r];
          if (leftp) wl_acc[r] += p[r]; else wr_acc[r] += p[r];
        }
        const unsigned int w01 = f2us2(p[0], p[1]);
        const unsigned int w23 = f2us2(p[2], p[3]);
        u16* pb = &Pw[qloc16 * 64 + (k & 7)];
        pb[0 * 64 + (((k >> 3) ^ ((qloc16 + 0) & 7)) * 8)] = (u16)w01;
        pb[1 * 64 + (((k >> 3) ^ ((qloc16 + 1) & 7)) * 8)] = (u16)(w01 >> 16);
        pb[2 * 64 + (((k >> 3) ^ ((qloc16 + 2) & 7)) * 8)] = (u16)w23;
        pb[3 * 64 + (((k >> 3) ^ ((qloc16 + 3) & 7)) * 8)] = (u16)(w23 >> 16);
      }
    } else {
#pragma unroll
      for (int tn = 0; tn < 4; tn++) {
        const int kg = k0 + tn * 16 + l15;
#pragma unroll
        for (int r = 0; r < 4; r++) {
          const int ql = qw + qloc16 + r;
          const int dlt = kg - (q0 + ql);
          const int jj = (dlt < -16 ? -16 : (dlt > 16 ? 16 : dlt)) + 16;
          const float p = __expf(sac[tn][r] + qrelJ[ql * 33 + jj]);
          l_acc[r] += p;
          if (dlt <= -16) wl_acc[r] += p;
          else if (dlt >= 16) wr_acc[r] += p;
          else wsum[ql * 31 + (dlt + 15)] = f2us(p);  // unique (q,j): no race
          const int k = tn * 16 + l15, q = qloc16 + r;
          Pw[q * 64 + (((k >> 3) ^ (q & 7)) * 8) + (k & 7)] = f2us(p);
        }
      }
    }

    WAIT_LGKM0();  // P strip is wave-private: DS in-order, no barrier needed

    // ---- O += P V ----
#pragma unroll
    for (int kk = 0; kk < 2; kk++) {
      const int ch = kk * 4 + l16;
      const short8 ap = *(const short8*)&Pw[l15 * 64 + ((ch ^ (l15 & 7)) * 8)];
#pragma unroll
      for (int tn = 0; tn < 4; tn++) {
        const int dd = tn * 16 + l15;
        const short8 bv = *(const short8*)&KVc[4096 + dd * 64 + ((ch ^ (dd & 7)) * 8)];
        Oacc[tn] = MFMA16(ap, bv, Oacc[tn]);
      }
    }
  }

  // ---- epilogue (all state wave-private) ----
#pragma unroll
  for (int r = 0; r < 4; r++) {
    l_acc[r] += __shfl_xor(l_acc[r], 1);
    l_acc[r] += __shfl_xor(l_acc[r], 2);
    l_acc[r] += __shfl_xor(l_acc[r], 4);
    l_acc[r] += __shfl_xor(l_acc[r], 8);
    wl_acc[r] += __shfl_xor(wl_acc[r], 1);
    wl_acc[r] += __shfl_xor(wl_acc[r], 2);
    wl_acc[r] += __shfl_xor(wl_acc[r], 4);
    wl_acc[r] += __shfl_xor(wl_acc[r], 8);
    wr_acc[r] += __shfl_xor(wr_acc[r], 1);
    wr_acc[r] += __shfl_xor(wr_acc[r], 2);
    wr_acc[r] += __shfl_xor(wr_acc[r], 4);
    wr_acc[r] += __shfl_xor(wr_acc[r], 8);
  }
  float linv[4];
#pragma unroll
  for (int r = 0; r < 4; r++) {
    linv[r] = 1.f / l_acc[r];
    wl_acc[r] *= linv[r];
    wr_acc[r] *= linv[r];
  }
#pragma unroll
  for (int tn = 0; tn < 4; tn++) {
    const int d = tn * 16 + l15;
    const float rv0 = relv[d];
    const float rv32 = relv[32 * 64 + d];
#pragma unroll
    for (int r = 0; r < 4; r++)
      Oacc[tn][r] = Oacc[tn][r] * linv[r] + wl_acc[r] * rv0 + wr_acc[r] * rv32;
  }
  for (int j = 1; j <= 31; j++) {
    float wv[4];
#pragma unroll
    for (int r = 0; r < 4; r++)
      wv[r] = us2f(wsum[(qw + qloc16 + r) * 31 + (j - 1)]) * linv[r];
#pragma unroll
    for (int tn = 0; tn < 4; tn++) {
      const float rv = relv[j * 64 + tn * 16 + l15];
#pragma unroll
      for (int r = 0; r < 4; r++) Oacc[tn][r] += wv[r] * rv;
    }
  }
#pragma unroll
  for (int tn = 0; tn < 4; tn++) {
    const int d = tn * 16 + l15;
#pragma unroll
    for (int r = 0; r < 4; r++) {
      const int sq = q0 + qw + qloc16 + r;
      ctx[((size_t)b * 2048 + sq) * 1024 + h * 64 + d] = f2us(Oacc[tn][r]);
    }
  }
}

// ---------------------------------------------------------------------------
extern "C" void kernel_launch(void* const* d_in, const int* in_sizes, int n_in,
                              void* d_out, int out_size, void* d_ws, size_t ws_size,
                              hipStream_t stream) {
  u16* qb = (u16*)d_ws;                 // [32][2048][64]
  u16* kb = qb + 4194304;               // [32][2048][64]
  u16* vtb = kb + 4194304;              // [32][64][2048]  (V transposed)
  u16* ctx = vtb + 4194304;             // [2][2048][1024]
  u16* Xq = ctx + 4194304;
  u16* Xk = Xq + 4194304;
  u16* Xv = Xk + 4194304;
  u16* Wqb = Xv + 4194304;
  u16* Wkb = Wqb + 1048576;
  u16* Wvb = Wkb + 1048576;
  u16* Wob = Wvb + 1048576;

  const float* bq = (const float*)d_in[4];
  const float* bk = (const float*)d_in[6];
  const float* bv = (const float*)d_in[8];
  const float* bo = (const float*)d_in[10];
  const float* relk = (const float*)d_in[11];
  const float* relv = (const float*)d_in[12];

  dim3 blk(256);
  cvt_all_kernel<<<dim3(2048, 1, 7), blk, 0, stream>>>(
      (const float*)d_in[0], (const float*)d_in[1], (const float*)d_in[2],
      (const float*)d_in[3], (const float*)d_in[5], (const float*)d_in[7],
      (const float*)d_in[9], Xq, Xk, Xv, Wqb, Wkb, Wvb, Wob);
  qkv_kernel<<<dim3(32, 8, 3), blk, 0, stream>>>(Xq, Xk, Xv, Wqb, Wkb, Wvb, bq,
                                                 bk, bv, qb, kb, vtb);
  attn_kernel<<<dim3(32, 32), blk, 0, stream>>>(qb, kb, vtb, relk, relv, ctx);
  oproj_kernel<<<dim3(32, 8), blk, 0, stream>>>(ctx, Wob, bo, (float*)d_out);
}

// Round 7
// 281.268 us; speedup vs baseline: 2.1013x; 1.2352x over previous
//
#include <hip/hip_runtime.h>
#include <hip/hip_bf16.h>

typedef unsigned short u16;
typedef __attribute__((ext_vector_type(8))) short short8;
typedef __attribute__((ext_vector_type(4))) short short4_t;
typedef __attribute__((ext_vector_type(4))) float f32x4;

#define MFMA16(a, b, c) __builtin_amdgcn_mfma_f32_16x16x32_bf16((a), (b), (c), 0, 0, 0)

// K=16 bf16 MFMA (for PV with P^T directly from S^T's C-layout registers)
#if __has_builtin(__builtin_amdgcn_mfma_f32_16x16x16bf16_1k)
#define MFMAK16(a, b, c) __builtin_amdgcn_mfma_f32_16x16x16bf16_1k((a), (b), (c), 0, 0, 0)
#elif __has_builtin(__builtin_amdgcn_mfma_f32_16x16x16_bf16)
#define MFMAK16(a, b, c) __builtin_amdgcn_mfma_f32_16x16x16_bf16((a), (b), (c), 0, 0, 0)
#else
__device__ __forceinline__ f32x4 mfmak16_asm(short4_t a, short4_t b, f32x4 c) {
  asm("v_mfma_f32_16x16x16_bf16 %0, %1, %2, %0" : "+v"(c) : "v"(a), "v"(b));
  return c;
}
#define MFMAK16(a, b, c) mfmak16_asm((a), (b), (c))
#endif

#define GLOAD_LDS16(gp, lp)                                          \
  __builtin_amdgcn_global_load_lds(                                  \
      (const __attribute__((address_space(1))) void*)(gp),           \
      (__attribute__((address_space(3))) void*)(lp), 16, 0, 0)
#define SBAR() asm volatile("s_barrier" ::: "memory")
#define WAIT_LGKM0() asm volatile("s_waitcnt lgkmcnt(0)" ::: "memory")

__device__ __forceinline__ float us2f(u16 u) {
  union { unsigned int i; float f; } c; c.i = ((unsigned int)u) << 16; return c.f;
}
__device__ __forceinline__ u16 f2us(float f) {
  union { float f; unsigned int i; } c; c.f = f;
  return (u16)((c.i + 0x7fffu + ((c.i >> 16) & 1u)) >> 16);
}
// packed 2xf32 -> 2xbf16 (v_cvt_pk_bf16_f32); a low 16, b high 16
__device__ __forceinline__ unsigned int f2us2(float a, float b) {
  union { __hip_bfloat162 h; unsigned int u; } c;
  c.h = __float22bfloat162_rn(float2{a, b});
  return c.u;
}

// ---------------------------------------------------------------------------
// Fused f32 -> bf16 convert for the 7 big tensors (X q/k/v + 4 weights).
// ---------------------------------------------------------------------------
__global__ __launch_bounds__(256) void cvt_all_kernel(
    const float* x0, const float* x1, const float* x2, const float* w0,
    const float* w1, const float* w2, const float* w3, u16* y0, u16* y1,
    u16* y2, u16* z0, u16* z1, u16* z2, u16* z3) {
  const int z = blockIdx.z;
  const float* src; u16* dst; int n;
  switch (z) {
    case 0: src = x0; dst = y0; n = 4194304; break;
    case 1: src = x1; dst = y1; n = 4194304; break;
    case 2: src = x2; dst = y2; n = 4194304; break;
    case 3: src = w0; dst = z0; n = 1048576; break;
    case 4: src = w1; dst = z1; n = 1048576; break;
    case 5: src = w2; dst = z2; n = 1048576; break;
    default: src = w3; dst = z3; n = 1048576; break;
  }
  const int i = (blockIdx.x * 256 + threadIdx.x) * 8;
  if (i < n) {
    const float4 a = *(const float4*)(src + i);
    const float4 b = *(const float4*)(src + i + 4);
    unsigned int o[4];
    o[0] = f2us2(a.x, a.y); o[1] = f2us2(a.z, a.w);
    o[2] = f2us2(b.x, b.y); o[3] = f2us2(b.z, b.w);
    *(uint4*)(dst + i) = *(uint4*)o;
  }
}

// relk [33][64] f32 -> relkb [64][64] bf16 (rows 33..63 zero, for MFMA B-op)
__global__ __launch_bounds__(256) void cvt_relk_kernel(const float* relk, u16* relkb) {
  const int i = blockIdx.x * 256 + threadIdx.x;
  if (i < 4096) relkb[i] = (i < 2112) ? f2us(relk[i]) : (u16)0;
}

// ---------------------------------------------------------------------------
// GEMM: Y = X @ W^T + bias (validated r3-r6).
// SCATTER && vt:  Y layout [bh][d][s]  (V transposed for attention B-operand)
// SCATTER && !vt: Y layout [bh][s][d]
// ---------------------------------------------------------------------------
template <bool SCATTER, typename OUT>
__device__ __forceinline__ void gemm_body(const u16* __restrict__ X,
                                          const u16* __restrict__ W,
                                          const float* __restrict__ bias,
                                          OUT* __restrict__ Y, int row0, int col0,
                                          bool vt) {
  __shared__ __align__(16) u16 As[128 * 64];
  __shared__ __align__(16) u16 Bs[128 * 64];
  const int tid = threadIdx.x;
  const int lane = tid & 63;
  const int wid = tid >> 6;
  const int wm = wid >> 1, wn = wid & 1;
  const int l15 = lane & 15, l16 = lane >> 4;
  const int lrow = lane >> 3;
  const int lchunk = (lane & 7) ^ lrow;

  f32x4 acc[4][4];
#pragma unroll
  for (int i = 0; i < 4; i++)
#pragma unroll
    for (int j = 0; j < 4; j++) acc[i][j] = (f32x4){0.f, 0.f, 0.f, 0.f};

  for (int k0 = 0; k0 < 1024; k0 += 64) {
#pragma unroll
    for (int i = 0; i < 4; i++) {
      const int rb = wid * 32 + i * 8;
      GLOAD_LDS16(X + (size_t)(row0 + rb + lrow) * 1024 + k0 + lchunk * 8, &As[rb * 64]);
      GLOAD_LDS16(W + (size_t)(col0 + rb + lrow) * 1024 + k0 + lchunk * 8, &Bs[rb * 64]);
    }
    __syncthreads();
#pragma unroll
    for (int kk = 0; kk < 2; kk++) {
      const int ch = kk * 4 + l16;
      short8 af[4], bfr[4];
#pragma unroll
      for (int t = 0; t < 4; t++) {
        const int m = wm * 64 + t * 16 + l15;
        af[t] = *(const short8*)&As[m * 64 + ((ch ^ (m & 7)) * 8)];
        const int n = wn * 64 + t * 16 + l15;
        bfr[t] = *(const short8*)&Bs[n * 64 + ((ch ^ (n & 7)) * 8)];
      }
#pragma unroll
      for (int tm = 0; tm < 4; tm++)
#pragma unroll
        for (int tn = 0; tn < 4; tn++)
          acc[tm][tn] = MFMA16(af[tm], bfr[tn], acc[tm][tn]);
    }
    __syncthreads();
  }

#pragma unroll
  for (int tn = 0; tn < 4; tn++) {
    const int col = col0 + wn * 64 + tn * 16 + l15;
    const float bv = bias[col];
#pragma unroll
    for (int tm = 0; tm < 4; tm++) {
      const int rowb = row0 + wm * 64 + tm * 16 + l16 * 4;  // rows rowb..rowb+3
      if (SCATTER) {
        const int bb = rowb >> 11, ss = rowb & 2047;
        const int hh = col >> 6, dd = col & 63;
        if (vt) {
          unsigned int o[2];
          o[0] = f2us2(acc[tm][tn][0] + bv, acc[tm][tn][1] + bv);
          o[1] = f2us2(acc[tm][tn][2] + bv, acc[tm][tn][3] + bv);
          *(short4_t*)&((u16*)Y)[(((size_t)(bb * 16 + hh)) * 64 + dd) * 2048 + ss] =
              *(short4_t*)o;
        } else {
#pragma unroll
          for (int r = 0; r < 4; r++)
            ((u16*)Y)[(((size_t)(bb * 16 + hh)) * 2048 + ss + r) * 64 + dd] =
                f2us(acc[tm][tn][r] + bv);
        }
      } else {
#pragma unroll
        for (int r = 0; r < 4; r++)
          Y[(size_t)(rowb + r) * 1024 + col] = (OUT)(acc[tm][tn][r] + bv);
      }
    }
  }
}

__global__ __launch_bounds__(256) void qkv_kernel(
    const u16* Xq, const u16* Xk, const u16* Xv, const u16* Wq, const u16* Wk,
    const u16* Wv, const float* bq, const float* bk, const float* bv, u16* Yq,
    u16* Yk, u16* Yv) {
  const int z = blockIdx.z;
  const u16* X = z == 0 ? Xq : (z == 1 ? Xk : Xv);
  const u16* W = z == 0 ? Wq : (z == 1 ? Wk : Wv);
  const float* bi = z == 0 ? bq : (z == 1 ? bk : bv);
  u16* Y = z == 0 ? Yq : (z == 1 ? Yk : Yv);
  gemm_body<true, u16>(X, W, bi, Y, blockIdx.x * 128, blockIdx.y * 128, z == 2);
}

__global__ __launch_bounds__(256) void oproj_kernel(const u16* Xc, const u16* Wo,
                                                    const float* bo, float* out) {
  gemm_body<false, float>(Xc, Wo, bo, out, blockIdx.x * 128, blockIdx.y * 128, false);
}

// ---------------------------------------------------------------------------
// Flash attention (rel-pos, no online softmax — r4-validated bounds).
// r7: TRANSPOSED score trick. S^T = K·Q^T (swapped MFMA operands; free).
// P^T then sits in C-layout [k=tn*16+quad*4+r][q=l&15] == the B-operand
// layout of v_mfma_f32_16x16x16_bf16, so O^T += V^T·P^T runs directly from
// registers: exp -> pack -> MFMA. The per-tile LDS P round-trip + lgkm drain
// (r4/r6's latency wall) is GONE. V^T A-frags via ds_read_b64 from the
// staged, swizzled V tile. l/wl/wr are single regs (q fixed per lane).
// qrel prologue is now a 6-MFMA GEMM vs bf16 relkb.
// LDS = 40960 B exactly -> 4 blocks/CU. grid.x = bh -> same-XCD L2 reuse.
// ---------------------------------------------------------------------------
__global__ __launch_bounds__(256) void attn_kernel(
    const u16* __restrict__ Qg, const u16* __restrict__ Kg,
    const u16* __restrict__ Vtg, const u16* __restrict__ relkb,
    const float* __restrict__ relv, u16* __restrict__ ctx) {
  __shared__ __align__(16) u16 KVs[2][8192];   // per buf: K [0,4096), V^T [4096,8192)
  __shared__ __align__(4) u16 qrelJ[64 * 33];  // Q[q]·relk[j], bf16 (wave-private rows)
  __shared__ __align__(4) u16 wsum[64 * 31];   // in-band p, write-once

  const int tid = threadIdx.x, lane = tid & 63, wid = tid >> 6;
  const int l15 = lane & 15, l16 = lane >> 4;
  const int bh = blockIdx.x;  // x = bh: same-bh -> same XCD L2
  const int b = bh >> 4, h = bh & 15;
  const int q0 = blockIdx.y * 64;
  const u16* Qb = Qg + (size_t)bh * 2048 * 64;
  const u16* Kb = Kg + (size_t)bh * 2048 * 64;
  const u16* Vtb = Vtg + (size_t)bh * 64 * 2048;  // [d][s]

  const int lrow = lane >> 3;
  const int lchunk = (lane & 7) ^ lrow;
  const int qw = wid * 16;
  const int kq4 = l16 * 4;          // quad*4 (k-local / d-local row base)
  const int qrow = qw + l15;        // this lane's q row (S^T orientation)

  u16* Qs = &KVs[1][0];  // Q aliases buf1 (prologue-only; overwritten at kt=0 prefetch)

  // ---- prologue: stage Q, zero wsum ----
#pragma unroll
  for (int i = 0; i < 2; i++) {
    const int rb = wid * 16 + i * 8;
    GLOAD_LDS16(Qb + (size_t)(q0 + rb + lrow) * 64 + lchunk * 8, &Qs[rb * 64]);
  }
  for (int idx = tid; idx < 64 * 31 / 2; idx += 256) ((unsigned int*)wsum)[idx] = 0u;
  __syncthreads();  // Q staged (vmcnt drained), wsum zeroed

  // ---- hoist Q fragment ----
  short8 aq[2];
  {
    const int m = qw + l15;
    aq[0] = *(const short8*)&Qs[m * 64 + ((l16 ^ (m & 7)) * 8)];
    aq[1] = *(const short8*)&Qs[m * 64 + (((4 + l16) ^ (m & 7)) * 8)];
  }

  // ---- prefetch tile 0 -> buf0 ----
#pragma unroll
  for (int i = 0; i < 2; i++) {
    const int rb = wid * 16 + i * 8;
    GLOAD_LDS16(Kb + (size_t)(rb + lrow) * 64 + lchunk * 8, &KVs[0][rb * 64]);
  }
#pragma unroll
  for (int i = 0; i < 2; i++) {
    const int rb = wid * 16 + i * 8;
    GLOAD_LDS16(Vtb + (size_t)(rb + lrow) * 2048 + lchunk * 8, &KVs[0][4096 + rb * 64]);
  }

  // ---- qrel GEMM: qrelJ[q][j] = Q[q]·relk[j] (wave's own 16 q-rows) ----
  {
    f32x4 qa[3];
#pragma unroll
    for (int nt = 0; nt < 3; nt++) {
      qa[nt] = (f32x4){0.f, 0.f, 0.f, 0.f};
#pragma unroll
      for (int kk = 0; kk < 2; kk++) {
        const short8 bf =
            *(const short8*)(relkb + (nt * 16 + l15) * 64 + kk * 32 + l16 * 8);
        qa[nt] = MFMA16(aq[kk], bf, qa[nt]);
      }
    }
#pragma unroll
    for (int nt = 0; nt < 3; nt++) {
      if (nt < 2 || l15 == 0) {
#pragma unroll
        for (int r = 0; r < 4; r++)
          qrelJ[(qw + kq4 + r) * 33 + nt * 16 + l15] = f2us(qa[nt][r]);
      }
    }
  }
  WAIT_LGKM0();  // aq reads + qrelJ writes landed (before buf1 overwrite / reads)
  const float q0r = us2f(qrelJ[qrow * 33 + 0]);    // bias for dlt<=-16
  const float q32r = us2f(qrelJ[qrow * 33 + 32]);  // bias for dlt>=+16

  float l_acc = 0.f, wl_acc = 0.f, wr_acc = 0.f;
  f32x4 Oacc[4];
#pragma unroll
  for (int t = 0; t < 4; t++) Oacc[t] = (f32x4){0.f, 0.f, 0.f, 0.f};

  for (int kt = 0; kt < 32; kt++) {
    SBAR();  // all waves done with prev tile's buffer
    u16* KVc = &KVs[kt & 1][0];
    u16* KVn = &KVs[(kt & 1) ^ 1][0];
    if (kt < 31) {
      const int kn = (kt + 1) * 64;
#pragma unroll
      for (int i = 0; i < 2; i++) {
        const int rb = wid * 16 + i * 8;
        GLOAD_LDS16(Kb + (size_t)(kn + rb + lrow) * 64 + lchunk * 8, &KVn[rb * 64]);
      }
#pragma unroll
      for (int i = 0; i < 2; i++) {
        const int rb = wid * 16 + i * 8;
        GLOAD_LDS16(Vtb + (size_t)(rb + lrow) * 2048 + kn + lchunk * 8,
                    &KVn[4096 + rb * 64]);
      }
      asm volatile("s_waitcnt vmcnt(4)" ::: "memory");  // own tile-kt loads done
    } else {
      asm volatile("s_waitcnt vmcnt(0)" ::: "memory");
    }
    SBAR();  // every wave's tile-kt data is in LDS

    const int k0 = kt * 64;

    // ---- S^T = K·Q^T (swapped operands) ----
    f32x4 sac[4];
#pragma unroll
    for (int t = 0; t < 4; t++) sac[t] = (f32x4){0.f, 0.f, 0.f, 0.f};
#pragma unroll
    for (int kk = 0; kk < 2; kk++) {
      const int ch = kk * 4 + l16;
#pragma unroll
      for (int tn = 0; tn < 4; tn++) {
        const int n = tn * 16 + l15;
        const short8 bk = *(const short8*)&KVc[n * 64 + ((ch ^ (n & 7)) * 8)];
        sac[tn] = MFMA16(bk, aq[kk], sac[tn]);
      }
    }

    // ---- p = exp(s + bias) in-register; bookkeeping ----
    float p[4][4];
    if (k0 + 79 <= q0 || k0 >= q0 + 79) {
      const float eb = (k0 < q0) ? q0r : q32r;
      float ts = 0.f;
#pragma unroll
      for (int tn = 0; tn < 4; tn++)
#pragma unroll
        for (int r = 0; r < 4; r++) {
          p[tn][r] = __expf(sac[tn][r] + eb);
          ts += p[tn][r];
        }
      l_acc += ts;
      if (k0 < q0) wl_acc += ts; else wr_acc += ts;
    } else {
#pragma unroll
      for (int tn = 0; tn < 4; tn++) {
#pragma unroll
        for (int r = 0; r < 4; r++) {
          const int kg = k0 + tn * 16 + kq4 + r;
          const int dlt = kg - (q0 + qrow);
          const int jj = (dlt < -16 ? -16 : (dlt > 16 ? 16 : dlt)) + 16;
          const float pv = __expf(sac[tn][r] + us2f(qrelJ[qrow * 33 + jj]));
          p[tn][r] = pv;
          l_acc += pv;
          if (dlt <= -16) wl_acc += pv;
          else if (dlt >= 16) wr_acc += pv;
          else wsum[qrow * 31 + (dlt + 15)] = f2us(pv);  // unique (q,k): no race
        }
      }
    }

    // ---- pack P^T fragments (= B-operand of K=16 MFMA) ----
    short4_t pf[4];
#pragma unroll
    for (int tn = 0; tn < 4; tn++) {
      union { unsigned int u[2]; short4_t s; } c;
      c.u[0] = f2us2(p[tn][0], p[tn][1]);
      c.u[1] = f2us2(p[tn][2], p[tn][3]);
      pf[tn] = c.s;
    }

    // ---- O^T += V^T · P^T (A-frags: ds_read_b64 from swizzled V^T tile) ----
#pragma unroll
    for (int td = 0; td < 4; td++) {
      const int row = td * 16 + l15;  // d-local row
      const int rs = row & 7;
#pragma unroll
      for (int kk = 0; kk < 4; kk++) {
        const short4_t vf = *(const short4_t*)&KVc[4096 + row * 64 +
                                                   (((kk * 2 + (l16 >> 1)) ^ rs) * 8) +
                                                   (l16 & 1) * 4];
        Oacc[td] = MFMAK16(vf, pf[kk], Oacc[td]);
      }
    }
  }

  // ---- epilogue (lane owns q = qrow; reduce over the 4 quads) ----
  l_acc += __shfl_xor(l_acc, 16); l_acc += __shfl_xor(l_acc, 32);
  wl_acc += __shfl_xor(wl_acc, 16); wl_acc += __shfl_xor(wl_acc, 32);
  wr_acc += __shfl_xor(wr_acc, 16); wr_acc += __shfl_xor(wr_acc, 32);
  const float linv = 1.f / l_acc;
  wl_acc *= linv; wr_acc *= linv;

#pragma unroll
  for (int td = 0; td < 4; td++) {
    const f32x4 rv0 = *(const f32x4*)&relv[td * 16 + kq4];
    const f32x4 rv32 = *(const f32x4*)&relv[32 * 64 + td * 16 + kq4];
#pragma unroll
    for (int r = 0; r < 4; r++)
      Oacc[td][r] = Oacc[td][r] * linv + wl_acc * rv0[r] + wr_acc * rv32[r];
  }
  for (int j = 1; j <= 31; j++) {
    const float wv = us2f(wsum[qrow * 31 + (j - 1)]) * linv;
#pragma unroll
    for (int td = 0; td < 4; td++) {
      const f32x4 rv = *(const f32x4*)&relv[j * 64 + td * 16 + kq4];
#pragma unroll
      for (int r = 0; r < 4; r++) Oacc[td][r] += wv * rv[r];
    }
  }
  const size_t srow = ((size_t)b * 2048 + q0 + qrow) * 1024 + h * 64;
#pragma unroll
  for (int td = 0; td < 4; td++)
#pragma unroll
    for (int r = 0; r < 4; r++)
      ctx[srow + td * 16 + kq4 + r] = f2us(Oacc[td][r]);
}

// ---------------------------------------------------------------------------
extern "C" void kernel_launch(void* const* d_in, const int* in_sizes, int n_in,
                              void* d_out, int out_size, void* d_ws, size_t ws_size,
                              hipStream_t stream) {
  u16* qb = (u16*)d_ws;                 // [32][2048][64]
  u16* kb = qb + 4194304;               // [32][2048][64]
  u16* vtb = kb + 4194304;              // [32][64][2048]  (V transposed)
  u16* ctx = vtb + 4194304;             // [2][2048][1024]
  u16* Xq = ctx + 4194304;
  u16* Xk = Xq + 4194304;
  u16* Xv = Xk + 4194304;
  u16* Wqb = Xv + 4194304;
  u16* Wkb = Wqb + 1048576;
  u16* Wvb = Wkb + 1048576;
  u16* Wob = Wvb + 1048576;
  u16* relkb = Wob + 1048576;           // [64][64] bf16, rows 33..63 zero

  const float* bq = (const float*)d_in[4];
  const float* bk = (const float*)d_in[6];
  const float* bv = (const float*)d_in[8];
  const float* bo = (const float*)d_in[10];
  const float* relk = (const float*)d_in[11];
  const float* relv = (const float*)d_in[12];

  dim3 blk(256);
  cvt_all_kernel<<<dim3(2048, 1, 7), blk, 0, stream>>>(
      (const float*)d_in[0], (const float*)d_in[1], (const float*)d_in[2],
      (const float*)d_in[3], (const float*)d_in[5], (const float*)d_in[7],
      (const float*)d_in[9], Xq, Xk, Xv, Wqb, Wkb, Wvb, Wob);
  cvt_relk_kernel<<<16, blk, 0, stream>>>(relk, relkb);
  qkv_kernel<<<dim3(32, 8, 3), blk, 0, stream>>>(Xq, Xk, Xv, Wqb, Wkb, Wvb, bq,
                                                 bk, bv, qb, kb, vtb);
  attn_kernel<<<dim3(32, 32), blk, 0, stream>>>(qb, kb, vtb, relkb, relv, ctx);
  oproj_kernel<<<dim3(32, 8), blk, 0, stream>>>(ctx, Wob, bo, (float*)d_out);
}

// Round 8
// 269.734 us; speedup vs baseline: 2.1911x; 1.0428x over previous
//
#include <hip/hip_runtime.h>
#include <hip/hip_bf16.h>

typedef unsigned short u16;
typedef __attribute__((ext_vector_type(8))) short short8;
typedef __attribute__((ext_vector_type(4))) short short4_t;
typedef __attribute__((ext_vector_type(4))) float f32x4;

#define MFMA16(a, b, c) __builtin_amdgcn_mfma_f32_16x16x32_bf16((a), (b), (c), 0, 0, 0)

#if __has_builtin(__builtin_amdgcn_mfma_f32_16x16x16bf16_1k)
#define MFMAK16(a, b, c) __builtin_amdgcn_mfma_f32_16x16x16bf16_1k((a), (b), (c), 0, 0, 0)
#elif __has_builtin(__builtin_amdgcn_mfma_f32_16x16x16_bf16)
#define MFMAK16(a, b, c) __builtin_amdgcn_mfma_f32_16x16x16_bf16((a), (b), (c), 0, 0, 0)
#else
__device__ __forceinline__ f32x4 mfmak16_asm(short4_t a, short4_t b, f32x4 c) {
  asm("v_mfma_f32_16x16x16_bf16 %0, %1, %2, %0" : "+v"(c) : "v"(a), "v"(b));
  return c;
}
#define MFMAK16(a, b, c) mfmak16_asm((a), (b), (c))
#endif

#define GLOAD_LDS16(gp, lp)                                          \
  __builtin_amdgcn_global_load_lds(                                  \
      (const __attribute__((address_space(1))) void*)(gp),           \
      (__attribute__((address_space(3))) void*)(lp), 16, 0, 0)
#define SBAR() asm volatile("s_barrier" ::: "memory")
#define WAIT_LGKM0() asm volatile("s_waitcnt lgkmcnt(0)" ::: "memory")
#define WAIT_VM0() asm volatile("s_waitcnt vmcnt(0)" ::: "memory")

__device__ __forceinline__ float us2f(u16 u) {
  union { unsigned int i; float f; } c; c.i = ((unsigned int)u) << 16; return c.f;
}
__device__ __forceinline__ u16 f2us(float f) {
  union { float f; unsigned int i; } c; c.f = f;
  return (u16)((c.i + 0x7fffu + ((c.i >> 16) & 1u)) >> 16);
}
__device__ __forceinline__ unsigned int f2us2(float a, float b) {
  union { __hip_bfloat162 h; unsigned int u; } c;
  c.h = __float22bfloat162_rn(float2{a, b});
  return c.u;
}

// ---------------------------------------------------------------------------
// Fused f32 -> bf16 convert for the 7 big tensors.
// ---------------------------------------------------------------------------
__global__ __launch_bounds__(256) void cvt_all_kernel(
    const float* x0, const float* x1, const float* x2, const float* w0,
    const float* w1, const float* w2, const float* w3, u16* y0, u16* y1,
    u16* y2, u16* z0, u16* z1, u16* z2, u16* z3) {
  const int z = blockIdx.z;
  const float* src; u16* dst; int n;
  switch (z) {
    case 0: src = x0; dst = y0; n = 4194304; break;
    case 1: src = x1; dst = y1; n = 4194304; break;
    case 2: src = x2; dst = y2; n = 4194304; break;
    case 3: src = w0; dst = z0; n = 1048576; break;
    case 4: src = w1; dst = z1; n = 1048576; break;
    case 5: src = w2; dst = z2; n = 1048576; break;
    default: src = w3; dst = z3; n = 1048576; break;
  }
  const int i = (blockIdx.x * 256 + threadIdx.x) * 8;
  if (i < n) {
    const float4 a = *(const float4*)(src + i);
    const float4 b = *(const float4*)(src + i + 4);
    unsigned int o[4];
    o[0] = f2us2(a.x, a.y); o[1] = f2us2(a.z, a.w);
    o[2] = f2us2(b.x, b.y); o[3] = f2us2(b.z, b.w);
    *(uint4*)(dst + i) = *(uint4*)o;
  }
}

// relk [33][64] f32 -> relkb [64][64] bf16 (rows 33..63 zero)
__global__ __launch_bounds__(256) void cvt_relk_kernel(const float* relk, u16* relkb) {
  const int i = blockIdx.x * 256 + threadIdx.x;
  if (i < 4096) relkb[i] = (i < 2112) ? f2us(relk[i]) : (u16)0;
}

// ---------------------------------------------------------------------------
// GEMM: Y = X @ W^T + bias.  MODE 0: f32 row-major [4096][1024].
// MODE 1: u16 [bh][s][d].  MODE 2: u16 [bh][d][s].  Modes 1/2 write through
// an LDS transpose (2 passes of 64 rows) for fully-coalesced global stores.
// ---------------------------------------------------------------------------
template <int MODE, typename OUT>
__device__ __forceinline__ void gemm_body(u16* __restrict__ SM,
                                          const u16* __restrict__ X,
                                          const u16* __restrict__ W,
                                          const float* __restrict__ bias,
                                          OUT* __restrict__ Y, int row0, int col0) {
  u16* As = SM;            // [128][64]
  u16* Bs = SM + 8192;     // [128][64]
  const int tid = threadIdx.x;
  const int lane = tid & 63;
  const int wid = tid >> 6;
  const int wm = wid >> 1, wn = wid & 1;
  const int l15 = lane & 15, l16 = lane >> 4;
  const int lrow = lane >> 3;
  const int lchunk = (lane & 7) ^ lrow;

  f32x4 acc[4][4];
#pragma unroll
  for (int i = 0; i < 4; i++)
#pragma unroll
    for (int j = 0; j < 4; j++) acc[i][j] = (f32x4){0.f, 0.f, 0.f, 0.f};

  for (int k0 = 0; k0 < 1024; k0 += 64) {
#pragma unroll
    for (int i = 0; i < 4; i++) {
      const int rb = wid * 32 + i * 8;
      GLOAD_LDS16(X + (size_t)(row0 + rb + lrow) * 1024 + k0 + lchunk * 8, &As[rb * 64]);
      GLOAD_LDS16(W + (size_t)(col0 + rb + lrow) * 1024 + k0 + lchunk * 8, &Bs[rb * 64]);
    }
    __syncthreads();
#pragma unroll
    for (int kk = 0; kk < 2; kk++) {
      const int ch = kk * 4 + l16;
      short8 af[4], bfr[4];
#pragma unroll
      for (int t = 0; t < 4; t++) {
        const int m = wm * 64 + t * 16 + l15;
        af[t] = *(const short8*)&As[m * 64 + ((ch ^ (m & 7)) * 8)];
        const int n = wn * 64 + t * 16 + l15;
        bfr[t] = *(const short8*)&Bs[n * 64 + ((ch ^ (n & 7)) * 8)];
      }
#pragma unroll
      for (int tm = 0; tm < 4; tm++)
#pragma unroll
        for (int tn = 0; tn < 4; tn++)
          acc[tm][tn] = MFMA16(af[tm], bfr[tn], acc[tm][tn]);
    }
    __syncthreads();
  }

  if (MODE == 0) {
#pragma unroll
    for (int tn = 0; tn < 4; tn++) {
      const int col = col0 + wn * 64 + tn * 16 + l15;
      const float bv = bias[col];
#pragma unroll
      for (int tm = 0; tm < 4; tm++) {
        const int rowb = row0 + wm * 64 + tm * 16 + l16 * 4;
#pragma unroll
        for (int r = 0; r < 4; r++)
          Y[(size_t)(rowb + r) * 1024 + col] = (OUT)(acc[tm][tn][r] + bv);
      }
    }
  } else {
    // LDS-transpose epilogue, two 64-row passes. MODE1 tile: [srow][col] stride
    // 136 u16 (b64-aligned). MODE2 tile: [col][srow] stride 72 u16 (b128-aligned).
    u16* T = SM;
    const int bb = row0 >> 11;
    const int sbase = row0 & 2047;
#pragma unroll
    for (int pass = 0; pass < 2; pass++) {
      __syncthreads();
      if (wm == pass) {
#pragma unroll
        for (int tn = 0; tn < 4; tn++) {
          const int coll = wn * 64 + tn * 16 + l15;
          const float bv = bias[col0 + coll];
#pragma unroll
          for (int tm = 0; tm < 4; tm++) {
            if (MODE == 1) {
#pragma unroll
              for (int r = 0; r < 4; r++)
                T[(tm * 16 + l16 * 4 + r) * 136 + coll] = f2us(acc[tm][tn][r] + bv);
            } else {
              unsigned int o[2];
              o[0] = f2us2(acc[tm][tn][0] + bv, acc[tm][tn][1] + bv);
              o[1] = f2us2(acc[tm][tn][2] + bv, acc[tm][tn][3] + bv);
              *(short4_t*)&T[coll * 72 + tm * 16 + l16 * 4] = *(short4_t*)o;
            }
          }
        }
      }
      __syncthreads();
      if (MODE == 1) {
#pragma unroll
        for (int i = 0; i < 8; i++) {
          const int idx = tid + i * 256;           // 2048 chunks of 4 u16
          const int srow = idx >> 5, c4 = idx & 31;
          const short4_t v = *(const short4_t*)&T[srow * 136 + c4 * 4];
          const int col = col0 + c4 * 4;
          const int hh = col >> 6, dd = col & 63;
          const int s = sbase + pass * 64 + srow;
          *(short4_t*)&((u16*)Y)[(((size_t)(bb * 16 + hh)) * 2048 + s) * 64 + dd] = v;
        }
      } else {
#pragma unroll
        for (int i = 0; i < 4; i++) {
          const int idx = tid + i * 256;           // 1024 chunks of 8 u16
          const int cl = idx >> 3, sc = idx & 7;
          const short8 v = *(const short8*)&T[cl * 72 + sc * 8];
          const int col = col0 + cl;
          const int hh = col >> 6, dd = col & 63;
          const int s = sbase + pass * 64 + sc * 8;
          *(short8*)&((u16*)Y)[(((size_t)(bb * 16 + hh)) * 64 + dd) * 2048 + s] = v;
        }
      }
    }
  }
}

__global__ __launch_bounds__(256) void qkv_kernel(
    const u16* Xq, const u16* Xk, const u16* Xv, const u16* Wq, const u16* Wk,
    const u16* Wv, const float* bq, const float* bk, const float* bv, u16* Yq,
    u16* Yk, u16* Yv) {
  __shared__ __align__(16) u16 SM[16384];
  const int z = blockIdx.z;
  const u16* X = z == 0 ? Xq : (z == 1 ? Xk : Xv);
  const u16* W = z == 0 ? Wq : (z == 1 ? Wk : Wv);
  const float* bi = z == 0 ? bq : (z == 1 ? bk : bv);
  u16* Y = z == 0 ? Yq : (z == 1 ? Yk : Yv);
  if (z == 2)
    gemm_body<2, u16>(SM, X, W, bi, Y, blockIdx.x * 128, blockIdx.y * 128);
  else
    gemm_body<1, u16>(SM, X, W, bi, Y, blockIdx.x * 128, blockIdx.y * 128);
}

__global__ __launch_bounds__(256) void oproj_kernel(const u16* Xc, const u16* Wo,
                                                    const float* bo, float* out) {
  __shared__ __align__(16) u16 SM[16384];
  gemm_body<0, float>(SM, Xc, Wo, bo, out, blockIdx.x * 128, blockIdx.y * 128);
}

// ---------------------------------------------------------------------------
// Flash attention (S^T trick, no online softmax, rel-pos — r7 validated).
// r8: SINGLE-buffered K/V (16 KB) -> LDS 24576 B -> 6 blocks/CU (24 waves);
// implicit wave-level overlap replaces the double buffer (m97 philosophy).
// Fused exp->pack per tn cuts VGPRs. Coalesced ctx store via LDS transpose
// into the freed KV buffer at epilogue.
// ---------------------------------------------------------------------------
__global__ __launch_bounds__(256, 6) void attn_kernel(
    const u16* __restrict__ Qg, const u16* __restrict__ Kg,
    const u16* __restrict__ Vtg, const u16* __restrict__ relkb,
    const float* __restrict__ relv, u16* __restrict__ ctx) {
  __shared__ __align__(16) u16 KV[8192];       // K [0,4096), V^T [4096,8192)
  __shared__ __align__(16) u16 qrelJ[64 * 33]; // Q[q]·relk[j] bf16
  __shared__ __align__(16) u16 wsum[64 * 31];  // in-band p, write-once

  const int tid = threadIdx.x, lane = tid & 63, wid = tid >> 6;
  const int l15 = lane & 15, l16 = lane >> 4;
  const int bh = blockIdx.x;  // same-bh -> same XCD L2
  const int b = bh >> 4, h = bh & 15;
  const int q0 = blockIdx.y * 64;
  const u16* Qb = Qg + (size_t)bh * 2048 * 64;
  const u16* Kb = Kg + (size_t)bh * 2048 * 64;
  const u16* Vtb = Vtg + (size_t)bh * 64 * 2048;  // [d][s]

  const int lrow = lane >> 3;
  const int lchunk = (lane & 7) ^ lrow;
  const int qw = wid * 16;
  const int kq4 = l16 * 4;
  const int qrow = qw + l15;

  // ---- prologue: stage Q into KV, zero wsum ----
#pragma unroll
  for (int i = 0; i < 2; i++) {
    const int rb = wid * 16 + i * 8;
    GLOAD_LDS16(Qb + (size_t)(q0 + rb + lrow) * 64 + lchunk * 8, &KV[rb * 64]);
  }
  for (int idx = tid; idx < 992; idx += 256) ((unsigned int*)wsum)[idx] = 0u;
  __syncthreads();

  // ---- hoist Q fragment ----
  short8 aq[2];
  {
    const int m = qw + l15;
    aq[0] = *(const short8*)&KV[m * 64 + ((l16 ^ (m & 7)) * 8)];
    aq[1] = *(const short8*)&KV[m * 64 + (((4 + l16) ^ (m & 7)) * 8)];
  }
  // ---- qrel GEMM: qrelJ[q][j] = Q[q]·relk[j] ----
  {
    f32x4 qa[3];
#pragma unroll
    for (int nt = 0; nt < 3; nt++) {
      qa[nt] = (f32x4){0.f, 0.f, 0.f, 0.f};
#pragma unroll
      for (int kk = 0; kk < 2; kk++) {
        const short8 bf =
            *(const short8*)(relkb + (nt * 16 + l15) * 64 + kk * 32 + l16 * 8);
        qa[nt] = MFMA16(aq[kk], bf, qa[nt]);
      }
    }
#pragma unroll
    for (int nt = 0; nt < 3; nt++) {
      if (nt < 2 || l15 == 0) {
#pragma unroll
        for (int r = 0; r < 4; r++)
          qrelJ[(qw + kq4 + r) * 33 + nt * 16 + l15] = f2us(qa[nt][r]);
      }
    }
  }
  WAIT_LGKM0();  // aq reads + qrelJ writes drained before KV overwrite / reads
  const float q0r = us2f(qrelJ[qrow * 33 + 0]);
  const float q32r = us2f(qrelJ[qrow * 33 + 32]);

  float l_acc = 0.f, wl_acc = 0.f, wr_acc = 0.f;
  f32x4 Oacc[4];
#pragma unroll
  for (int t = 0; t < 4; t++) Oacc[t] = (f32x4){0.f, 0.f, 0.f, 0.f};

  for (int kt = 0; kt < 32; kt++) {
    SBAR();  // all waves done reading KV
    const int k0 = kt * 64;
#pragma unroll
    for (int i = 0; i < 2; i++) {
      const int rb = wid * 16 + i * 8;
      GLOAD_LDS16(Kb + (size_t)(k0 + rb + lrow) * 64 + lchunk * 8, &KV[rb * 64]);
    }
#pragma unroll
    for (int i = 0; i < 2; i++) {
      const int rb = wid * 16 + i * 8;
      GLOAD_LDS16(Vtb + (size_t)(rb + lrow) * 2048 + k0 + lchunk * 8,
                  &KV[4096 + rb * 64]);
    }
    WAIT_VM0();
    SBAR();  // tile visible to all waves

    // ---- S^T = K·Q^T, fused exp->pack per tn ----
    short4_t pf[4];
    if (k0 + 79 <= q0 || k0 >= q0 + 79) {
      const float eb = (k0 < q0) ? q0r : q32r;
      float ts = 0.f;
#pragma unroll
      for (int tn = 0; tn < 4; tn++) {
        f32x4 sac = (f32x4){0.f, 0.f, 0.f, 0.f};
#pragma unroll
        for (int kk = 0; kk < 2; kk++) {
          const int n = tn * 16 + l15;
          const short8 bk = *(const short8*)&KV[n * 64 + (((kk * 4 + l16) ^ (n & 7)) * 8)];
          sac = MFMA16(bk, aq[kk], sac);
        }
        float p0 = __expf(sac[0] + eb), p1 = __expf(sac[1] + eb);
        float p2 = __expf(sac[2] + eb), p3 = __expf(sac[3] + eb);
        ts += (p0 + p1) + (p2 + p3);
        union { unsigned int u[2]; short4_t s; } c;
        c.u[0] = f2us2(p0, p1);
        c.u[1] = f2us2(p2, p3);
        pf[tn] = c.s;
      }
      l_acc += ts;
      if (k0 < q0) wl_acc += ts; else wr_acc += ts;
    } else {
#pragma unroll
      for (int tn = 0; tn < 4; tn++) {
        f32x4 sac = (f32x4){0.f, 0.f, 0.f, 0.f};
#pragma unroll
        for (int kk = 0; kk < 2; kk++) {
          const int n = tn * 16 + l15;
          const short8 bk = *(const short8*)&KV[n * 64 + (((kk * 4 + l16) ^ (n & 7)) * 8)];
          sac = MFMA16(bk, aq[kk], sac);
        }
        float pv4[4];
#pragma unroll
        for (int r = 0; r < 4; r++) {
          const int kg = k0 + tn * 16 + kq4 + r;
          const int dlt = kg - (q0 + qrow);
          const int jj = (dlt < -16 ? -16 : (dlt > 16 ? 16 : dlt)) + 16;
          const float pv = __expf(sac[r] + us2f(qrelJ[qrow * 33 + jj]));
          pv4[r] = pv;
          l_acc += pv;
          if (dlt <= -16) wl_acc += pv;
          else if (dlt >= 16) wr_acc += pv;
          else wsum[qrow * 31 + (dlt + 15)] = f2us(pv);
        }
        union { unsigned int u[2]; short4_t s; } c;
        c.u[0] = f2us2(pv4[0], pv4[1]);
        c.u[1] = f2us2(pv4[2], pv4[3]);
        pf[tn] = c.s;
      }
    }

    // ---- O^T += V^T · P^T ----
#pragma unroll
    for (int td = 0; td < 4; td++) {
      const int row = td * 16 + l15;
      const int rs = row & 7;
#pragma unroll
      for (int kk = 0; kk < 4; kk++) {
        const short4_t vf = *(const short4_t*)&KV[4096 + row * 64 +
                                                  (((kk * 2 + (l16 >> 1)) ^ rs) * 8) +
                                                  (l16 & 1) * 4];
        Oacc[td] = MFMAK16(vf, pf[kk], Oacc[td]);
      }
    }
  }

  // ---- epilogue: reduce, rel_v add, coalesced store via KV transpose ----
  l_acc += __shfl_xor(l_acc, 16); l_acc += __shfl_xor(l_acc, 32);
  wl_acc += __shfl_xor(wl_acc, 16); wl_acc += __shfl_xor(wl_acc, 32);
  wr_acc += __shfl_xor(wr_acc, 16); wr_acc += __shfl_xor(wr_acc, 32);
  const float linv = 1.f / l_acc;
  wl_acc *= linv; wr_acc *= linv;

#pragma unroll
  for (int td = 0; td < 4; td++) {
    const f32x4 rv0 = *(const f32x4*)&relv[td * 16 + kq4];
    const f32x4 rv32 = *(const f32x4*)&relv[32 * 64 + td * 16 + kq4];
#pragma unroll
    for (int r = 0; r < 4; r++)
      Oacc[td][r] = Oacc[td][r] * linv + wl_acc * rv0[r] + wr_acc * rv32[r];
  }
  WAIT_LGKM0();
  for (int j = 1; j <= 31; j++) {
    const float wv = us2f(wsum[qrow * 31 + (j - 1)]) * linv;
#pragma unroll
    for (int td = 0; td < 4; td++) {
      const f32x4 rv = *(const f32x4*)&relv[j * 64 + td * 16 + kq4];
#pragma unroll
      for (int r = 0; r < 4; r++) Oacc[td][r] += wv * rv[r];
    }
  }
  SBAR();  // KV free for O-tile reuse (all waves past last k-tile reads)
  // O tile [q 64][d 64] stride 72 u16 (b128-aligned), wave-private q rows
#pragma unroll
  for (int td = 0; td < 4; td++) {
    unsigned int o[2];
    o[0] = f2us2(Oacc[td][0], Oacc[td][1]);
    o[1] = f2us2(Oacc[td][2], Oacc[td][3]);
    *(short4_t*)&KV[qrow * 72 + td * 16 + kq4] = *(short4_t*)o;
  }
  WAIT_LGKM0();
  SBAR();
#pragma unroll
  for (int i = 0; i < 2; i++) {
    const int idx = tid + i * 256;  // 512 chunks of 8 u16
    const int q = idx >> 3, sc = idx & 7;
    const short8 v = *(const short8*)&KV[q * 72 + sc * 8];
    *(short8*)&ctx[((size_t)b * 2048 + q0 + q) * 1024 + h * 64 + sc * 8] = v;
  }
}

// ---------------------------------------------------------------------------
extern "C" void kernel_launch(void* const* d_in, const int* in_sizes, int n_in,
                              void* d_out, int out_size, void* d_ws, size_t ws_size,
                              hipStream_t stream) {
  u16* qb = (u16*)d_ws;                 // [32][2048][64]
  u16* kb = qb + 4194304;               // [32][2048][64]
  u16* vtb = kb + 4194304;              // [32][64][2048]
  u16* ctx = vtb + 4194304;             // [2][2048][1024]
  u16* Xq = ctx + 4194304;
  u16* Xk = Xq + 4194304;
  u16* Xv = Xk + 4194304;
  u16* Wqb = Xv + 4194304;
  u16* Wkb = Wqb + 1048576;
  u16* Wvb = Wkb + 1048576;
  u16* Wob = Wvb + 1048576;
  u16* relkb = Wob + 1048576;           // [64][64] bf16

  const float* bq = (const float*)d_in[4];
  const float* bk = (const float*)d_in[6];
  const float* bv = (const float*)d_in[8];
  const float* bo = (const float*)d_in[10];
  const float* relk = (const float*)d_in[11];
  const float* relv = (const float*)d_in[12];

  dim3 blk(256);
  cvt_all_kernel<<<dim3(2048, 1, 7), blk, 0, stream>>>(
      (const float*)d_in[0], (const float*)d_in[1], (const float*)d_in[2],
      (const float*)d_in[3], (const float*)d_in[5], (const float*)d_in[7],
      (const float*)d_in[9], Xq, Xk, Xv, Wqb, Wkb, Wvb, Wob);
  cvt_relk_kernel<<<16, blk, 0, stream>>>(relk, relkb);
  qkv_kernel<<<dim3(32, 8, 3), blk, 0, stream>>>(Xq, Xk, Xv, Wqb, Wkb, Wvb, bq,
                                                 bk, bv, qb, kb, vtb);
  attn_kernel<<<dim3(32, 32), blk, 0, stream>>>(qb, kb, vtb, relkb, relv, ctx);
  oproj_kernel<<<dim3(32, 8), blk, 0, stream>>>(ctx, Wob, bo, (float*)d_out);
}